// Round 1
// 258.870 us; speedup vs baseline: 1.0055x; 1.0055x over previous
//
#include <hip/hip_runtime.h>
#include <math.h>

#define NVOX 110592   // 48*48*48

typedef _Float16 f16x8 __attribute__((ext_vector_type(8)));
typedef _Float16 f16x4 __attribute__((ext_vector_type(4)));
typedef _Float16 f16x2 __attribute__((ext_vector_type(2)));
typedef float    f32x4 __attribute__((ext_vector_type(4)));

__device__ __forceinline__ void fmas4(float4& a, const float4& xv, float p) {
    a.x = fmaf(xv.x, p, a.x);
    a.y = fmaf(xv.y, p, a.y);
    a.z = fmaf(xv.z, p, a.z);
    a.w = fmaf(xv.w, p, a.w);
}
__device__ __forceinline__ float comp4(const float4& v, int j) {
    return j == 0 ? v.x : (j == 1 ? v.y : (j == 2 ? v.z : v.w));
}

// XCD-aware bijective swizzle (MI355X: 8 XCDs, blocks round-robin by default).
// Requires gridDim.x % 8 == 0 (both 2304 and 4608 are).  Gives each XCD a
// contiguous slab of blocks -> output-line halves merge in one L2, and the
// 3x3 (dz,dy) neighborhood re-reads of xT/featT become L2 hits.
__device__ __forceinline__ int xcd_swizzle(int bx, int nwg) {
    int chunk = nwg >> 3;
    return (bx & 7) * chunk + (bx >> 3);
}

// ---------------------------------------------------------------------------
// K0a: weights.
//  w1 [64 oc][32 ci][27 tap] f32 -> w1h [64 oc][27 tap][32 ci] f16
//  w2 [216 oc][64 ci] f32       -> w2h [224 oc][64 ci] f16 (rows 216.. zero)
// ---------------------------------------------------------------------------
__global__ void k_prep(const float* __restrict__ w1, const float* __restrict__ w2,
                       _Float16* __restrict__ w1h, _Float16* __restrict__ w2h) {
    int e = blockIdx.x * 256 + threadIdx.x;
    if (e < 64 * 32 * 27) {
        int oc = e / 864;
        int r = e - oc * 864;
        int ci = r / 27;
        int tap = r - ci * 27;
        w1h[oc * 864 + tap * 32 + ci] = (_Float16)w1[e];
    }
    int e2 = e - 55296;
    if (e2 >= 0 && e2 < 224 * 64) {
        int oc = e2 >> 6, k = e2 & 63;
        w2h[e2] = (oc < 216) ? (_Float16)w2[oc * 64 + k] : (_Float16)0.f;
    }
}

// ---------------------------------------------------------------------------
// K0b: transpose+cast feat and x: [32 c][NVOX] f32 -> [NVOX][32 c] f16.
// ---------------------------------------------------------------------------
__global__ __launch_bounds__(256) void k_prepT(
    const float* __restrict__ feat, const float* __restrict__ x,
    _Float16* __restrict__ featT, _Float16* __restrict__ xT)
{
    __shared__ _Float16 tile[64 * 36];
    int bx = blockIdx.x;
    int which = bx >= 1728;
    int v0 = (which ? bx - 1728 : bx) * 64;
    const float* s = which ? x : feat;
    _Float16* dt = which ? xT : featT;
    int t = threadIdx.x;

    for (int i = t; i < 1024; i += 256) {
        int c2 = i >> 6, dv = i & 63;
        f16x2 v;
        v.x = (_Float16)s[(2 * c2) * NVOX + v0 + dv];
        v.y = (_Float16)s[(2 * c2 + 1) * NVOX + v0 + dv];
        *(f16x2*)(tile + dv * 36 + c2 * 2) = v;
    }
    __syncthreads();
    for (int i = t; i < 512; i += 256) {
        int dv = i >> 3, ch = i & 7;
        f16x4 v = *(const f16x4*)(tile + dv * 36 + ch * 4);
        *(f16x4*)(dt + (v0 + dv) * 32 + ch * 4) = v;
    }
}

// ---------------------------------------------------------------------------
// K1: conv3x3x3 (replicate pad) + SiLU via f16 MFMA 16x16x32.
// One block per (d,h) row (48 voxels). 4 waves; wave w -> oc strip w*16.
// XCD swizzle: adjacent (d,h) rows share 2/3 of their featT neighborhood ->
// keep them on the same XCD's L2.
// ---------------------------------------------------------------------------
__global__ __launch_bounds__(256, 4) void k_conv1(
    const _Float16* __restrict__ featT, const _Float16* __restrict__ w1h,
    const float* __restrict__ b1, _Float16* __restrict__ hout)
{
    __shared__ _Float16 flds[450 * 40];      // 36 KB
    int bx = xcd_swizzle(blockIdx.x, gridDim.x);
    int d = bx / 48, hh = bx - d * 48;
    int t = threadIdx.x;

    for (int i = t; i < 1800; i += 256) {
        int col = i >> 2, chunk = i & 3;     // col = dzdy*50 + px
        int dzdy = col / 50;
        int px = col - dzdy * 50;
        int dz = dzdy / 3, dy = dzdy - dz * 3;
        int zz = min(max(d + dz - 1, 0), 47);
        int yy = min(max(hh + dy - 1, 0), 47);
        int xx = min(max(px - 1, 0), 47);
        int vox = (zz * 48 + yy) * 48 + xx;
        *(f16x8*)(flds + col * 40 + chunk * 8) =
            *(const f16x8*)(featT + vox * 32 + chunk * 8);
    }
    __syncthreads();

    int wid = t >> 6;                        // 0..3 -> oc strip
    int lane = t & 63;
    int mcol = lane & 15;                    // A row (oc) / B col (px)
    int q = lane >> 4;                       // quad: k = q*8 + j

    const _Float16* wbase = w1h + (wid * 16 + mcol) * 864 + q * 8;

    f32x4 acc0 = {0.f, 0.f, 0.f, 0.f};
    f32x4 acc1 = {0.f, 0.f, 0.f, 0.f};
    f32x4 acc2 = {0.f, 0.f, 0.f, 0.f};

#pragma unroll 3
    for (int dzdy = 0; dzdy < 9; ++dzdy) {
        const _Float16* brow = flds + (dzdy * 50 + mcol) * 40 + q * 8;
        const _Float16* wrow = wbase + dzdy * 96;     // 3 taps * 32
#pragma unroll
        for (int dx = 0; dx < 3; ++dx) {
            f16x8 av = *(const f16x8*)(wrow + dx * 32);
            const _Float16* bb = brow + dx * 40;
            f16x8 b0 = *(const f16x8*)(bb);
            f16x8 b1v = *(const f16x8*)(bb + 16 * 40);
            f16x8 b2v = *(const f16x8*)(bb + 32 * 40);
            acc0 = __builtin_amdgcn_mfma_f32_16x16x32_f16(av, b0, acc0, 0, 0, 0);
            acc1 = __builtin_amdgcn_mfma_f32_16x16x32_f16(av, b1v, acc1, 0, 0, 0);
            acc2 = __builtin_amdgcn_mfma_f32_16x16x32_f16(av, b2v, acc2, 0, 0, 0);
        }
    }

    // epilogue: bias + SiLU -> f16, transpose via LDS, coalesced f16x8 store
    __syncthreads();
    _Float16* transh = flds;                  // [48 px][72 f16 stride]
    float4 bv = ((const float4*)b1)[wid * 4 + q];
    {
        f32x4 accs[3] = {acc0, acc1, acc2};
#pragma unroll
        for (int p = 0; p < 3; ++p) {
            int px = p * 16 + mcol;           // D: col = lane&15
            f16x4 o;
            float s;
            s = accs[p][0] + bv.x; o.x = (_Float16)(s / (1.f + __expf(-s)));
            s = accs[p][1] + bv.y; o.y = (_Float16)(s / (1.f + __expf(-s)));
            s = accs[p][2] + bv.z; o.z = (_Float16)(s / (1.f + __expf(-s)));
            s = accs[p][3] + bv.w; o.w = (_Float16)(s / (1.f + __expf(-s)));
            *(f16x4*)(transh + px * 72 + wid * 16 + q * 4) = o;  // row = q*4+reg
        }
    }
    __syncthreads();
    for (int i = t; i < 384; i += 256) {
        int c = i & 7, px = i >> 3;
        f16x8 v = *(const f16x8*)(transh + px * 72 + c * 8);
        ((f16x8*)hout)[(bx * 48 + px) * 8 + c] = v;
    }
}

// ---------------------------------------------------------------------------
// K2: conv1x1 (64->216) via f16 MFMA + softmax(27) + 27-tap combination.
// One block per 24-voxel half row.  XCD swizzle: the two half-row blocks that
// split each 128B output line, and the (dz,dy)-neighbor rows that share the
// xT neighborhood, become dispatch-adjacent on the SAME XCD.
// ---------------------------------------------------------------------------
__global__ __launch_bounds__(256, 4) void k_fused(
    const _Float16* __restrict__ xT, const _Float16* __restrict__ hws,
    const _Float16* __restrict__ w2h, const float* __restrict__ b2,
    float* __restrict__ out)
{
    __shared__ float smem[10056];            // 40.2 KB
    _Float16* hl = (_Float16*)(smem + 5376); // [32 vox][72] f16 (aliases xh)
    _Float16* xh = (_Float16*)(smem + 5376); // [234 col][40] f16
    int bx = xcd_swizzle(blockIdx.x, gridDim.x);
    int d = bx / 96;
    int r = bx - d * 96;
    int hh = r >> 1;
    int w0 = (r & 1) * 24;
    int t = threadIdx.x;
    int vox0 = (d * 48 + hh) * 48 + w0;

    // stage h tile [24][64] f16 -> stride 72; zero-pad vox 24..31
    if (t < 192) {
        int vox = t >> 3, c = t & 7;
        *(f16x8*)(hl + vox * 72 + c * 8) = ((const f16x8*)hws)[(vox0 + vox) * 8 + c];
    } else {
        int i = t - 192;
        int vox = 24 + (i >> 3), c = i & 7;
        f16x8 z = {0, 0, 0, 0, 0, 0, 0, 0};
        *(f16x8*)(hl + vox * 72 + c * 8) = z;
    }
    __syncthreads();

    // conv2 via MFMA: A = w2h [224][64], B = h tile. Wave w: M-tiles w,w+4,w+8,w+12
    {
        int wid = t >> 6, lane = t & 63;
        int mcol = lane & 15, q = lane >> 4;
        for (int mt = wid; mt < 14; mt += 4) {
            float bias[4];
#pragma unroll
            for (int rr = 0; rr < 4; ++rr) {
                int oc = mt * 16 + q * 4 + rr;
                bias[rr] = (oc < 216) ? b2[oc] : 0.f;
            }
            f32x4 acc0 = {bias[0], bias[1], bias[2], bias[3]};
            f32x4 acc1 = acc0;
#pragma unroll
            for (int ks = 0; ks < 2; ++ks) {
                f16x8 av = *(const f16x8*)(w2h + (mt * 16 + mcol) * 64 + ks * 32 + q * 8);
                f16x8 bv0 = *(const f16x8*)(hl + mcol * 72 + ks * 32 + q * 8);
                f16x8 bv1 = *(const f16x8*)(hl + (16 + mcol) * 72 + ks * 32 + q * 8);
                acc0 = __builtin_amdgcn_mfma_f32_16x16x32_f16(av, bv0, acc0, 0, 0, 0);
                acc1 = __builtin_amdgcn_mfma_f32_16x16x32_f16(av, bv1, acc1, 0, 0, 0);
            }
#pragma unroll
            for (int rr = 0; rr < 4; ++rr) {
                int oc = mt * 16 + q * 4 + rr;
                if (oc < 216) {
                    int sub = oc / 27;
                    int n = oc - sub * 27;
                    smem[(sub * 24 + mcol) * 28 + n] = acc0[rr];
                    int vox1 = 16 + mcol;
                    if (vox1 < 24)
                        smem[(sub * 24 + vox1) * 28 + n] = acc1[rr];
                }
            }
        }
    }
    __syncthreads();

    // stage x neighborhood from xT (overwrites h region): pure b128 copies
    for (int i = t; i < 936; i += 256) {
        int col = i >> 2, chunk = i & 3;     // col = dzdy*26 + px (234 cols)
        int dzdy = col / 26;
        int px = col - dzdy * 26;
        int dz = dzdy / 3, dy = dzdy - dz * 3;
        int zz = min(max(d + dz - 1, 0), 47);
        int yy = min(max(hh + dy - 1, 0), 47);
        int xx = min(max(w0 + px - 1, 0), 47);
        int vox = (zz * 48 + yy) * 48 + xx;
        *(f16x8*)(xh + col * 40 + chunk * 8) =
            *(const f16x8*)(xT + vox * 32 + chunk * 8);
    }
    // softmax over 27 taps, vectorized (192 independent (sub,vox) rows)
    if (t < 192) {
        int sub = t / 24;
        int vox = t - sub * 24;
        float4* p4p = (float4*)(smem + (sub * 24 + vox) * 28);
        float4 v[7];
#pragma unroll
        for (int g = 0; g < 7; ++g) v[g] = p4p[g];
        float mx = fmaxf(fmaxf(v[6].x, v[6].y), v[6].z);
#pragma unroll
        for (int g = 0; g < 6; ++g)
            mx = fmaxf(mx, fmaxf(fmaxf(v[g].x, v[g].y), fmaxf(v[g].z, v[g].w)));
        float s = 0.f;
#pragma unroll
        for (int g = 0; g < 7; ++g) {
            v[g].x = __expf(v[g].x - mx);
            v[g].y = __expf(v[g].y - mx);
            v[g].z = __expf(v[g].z - mx);
            v[g].w = __expf(v[g].w - mx);
        }
        v[6].w = 0.f;
#pragma unroll
        for (int g = 0; g < 7; ++g) s += v[g].x + v[g].y + v[g].z + v[g].w;
        float inv = 1.f / s;
#pragma unroll
        for (int g = 0; g < 7; ++g) {
            v[g].x *= inv; v[g].y *= inv; v[g].z *= inv; v[g].w *= inv;
            p4p[g] = v[g];
        }
    }
    __syncthreads();

    // C: out[c][2d+i][2h+j][2w+k] = sum_n p[sub][vox][n] * x[c][nb(vox,n)]
    float4* smem4 = (float4*)smem;
    int tx = t & 7, ty = t >> 3;
    int cq = ty & 7, sp = ty >> 3;           // sp -> (i,j)
    float4 acc[2][3];
#pragma unroll
    for (int s = 0; s < 2; ++s)
#pragma unroll
        for (int wi = 0; wi < 3; ++wi)
            acc[s][wi] = make_float4(0.f, 0.f, 0.f, 0.f);

#pragma unroll
    for (int g = 0; g < 7; ++g) {
        float4 p4[2][3];
#pragma unroll
        for (int s = 0; s < 2; ++s)
#pragma unroll
            for (int wi = 0; wi < 3; ++wi)
                p4[s][wi] = smem4[((sp * 2 + s) * 24 + tx + wi * 8) * 7 + g];
#pragma unroll
        for (int j = 0; j < 4; ++j) {
            int n = g * 4 + j;
            if (n < 27) {
                int dz = n / 9;
                int rem = n - dz * 9;
                int dy = rem / 3, dx = rem - dy * 3;
#pragma unroll
                for (int wi = 0; wi < 3; ++wi) {
                    int col = (dz * 3 + dy) * 26 + tx + wi * 8 + dx;
                    f16x4 xr = *(const f16x4*)(xh + col * 40 + cq * 4);
                    float4 xv = make_float4((float)xr.x, (float)xr.y,
                                            (float)xr.z, (float)xr.w);
                    fmas4(acc[0][wi], xv, comp4(p4[0][wi], j));
                    fmas4(acc[1][wi], xv, comp4(p4[1][wi], j));
                }
            }
        }
    }

    int i_ = sp >> 1, j_ = sp & 1;
    int rowz = 2 * d + i_;
    int rowy = 2 * hh + j_;
#pragma unroll
    for (int wi = 0; wi < 3; ++wi) {
        int wg = w0 + tx + wi * 8;
#pragma unroll
        for (int cc = 0; cc < 4; ++cc) {
            int c = cq * 4 + cc;
            float2 v;
            v.x = comp4(acc[0][wi], cc);     // k = 0
            v.y = comp4(acc[1][wi], cc);     // k = 1
            *(float2*)(out + (((size_t)c * 96 + rowz) * 96 + rowy) * 96 + 2 * wg) = v;
        }
    }
}

extern "C" void kernel_launch(void* const* d_in, const int* in_sizes, int n_in,
                              void* d_out, int out_size, void* d_ws, size_t ws_size,
                              hipStream_t stream) {
    const float* x    = (const float*)d_in[0];
    const float* feat = (const float*)d_in[1];
    const float* w1   = (const float*)d_in[2];
    const float* b1   = (const float*)d_in[3];
    const float* w2   = (const float*)d_in[4];
    const float* b2   = (const float*)d_in[5];
    float* out = (float*)d_out;

    _Float16* w1h   = (_Float16*)d_ws;                       // 110592 B
    _Float16* w2h   = (_Float16*)((char*)d_ws + 110592);     //  28672 B
    _Float16* featT = (_Float16*)((char*)d_ws + 139264);     // 7,077,888 B
    _Float16* xT    = (_Float16*)((char*)d_ws + 7217152);    // 7,077,888 B
    _Float16* hws   = (_Float16*)((char*)d_ws + 14295040);   // 14,155,776 B

    k_prep<<<272, 256, 0, stream>>>(w1, w2, w1h, w2h);
    k_prepT<<<3456, 256, 0, stream>>>(feat, x, featT, xT);
    k_conv1<<<2304, 256, 0, stream>>>(featT, w1h, b1, hws);
    k_fused<<<4608, 256, 0, stream>>>(xT, hws, w2h, b2, out);
}

// Round 3
// 247.568 us; speedup vs baseline: 1.0514x; 1.0457x over previous
//
#include <hip/hip_runtime.h>
#include <math.h>

#define NVOX 110592   // 48*48*48

typedef _Float16 f16x8 __attribute__((ext_vector_type(8)));
typedef _Float16 f16x4 __attribute__((ext_vector_type(4)));
typedef _Float16 f16x2 __attribute__((ext_vector_type(2)));
typedef float    f32x4 __attribute__((ext_vector_type(4)));

__device__ __forceinline__ void fmas4(float4& a, const float4& xv, float p) {
    a.x = fmaf(xv.x, p, a.x);
    a.y = fmaf(xv.y, p, a.y);
    a.z = fmaf(xv.z, p, a.z);
    a.w = fmaf(xv.w, p, a.w);
}
__device__ __forceinline__ float comp4(const float4& v, int j) {
    return j == 0 ? v.x : (j == 1 ? v.y : (j == 2 ? v.z : v.w));
}

// XCD-aware bijective swizzle (8 XCDs; grid % 8 == 0). Neighbor (d,h) rows
// share 2/3 of their featT/xT halo -> keep them on the same XCD's L2.
__device__ __forceinline__ int xcd_swizzle(int bx, int nwg) {
    int chunk = nwg >> 3;
    return (bx & 7) * chunk + (bx >> 3);
}

// ---------------------------------------------------------------------------
// K0: merged prep.
//  blocks [0,3456): transpose+cast feat/x [32 c][NVOX] f32 -> [NVOX][32 c] f16
//  blocks [3456,3728): weights
//   w1 [64][32][27] f32 -> w1h [64 oc][27 tap][32 ci] f16
//   w2 [216][64] f32    -> w2h [224 oc][64 ci] f16 (rows 216.. zero)
// ---------------------------------------------------------------------------
__global__ __launch_bounds__(256) void k_prep(
    const float* __restrict__ feat, const float* __restrict__ x,
    const float* __restrict__ w1, const float* __restrict__ w2,
    _Float16* __restrict__ featT, _Float16* __restrict__ xT,
    _Float16* __restrict__ w1h, _Float16* __restrict__ w2h)
{
    __shared__ _Float16 tile[64 * 36];
    int bx = blockIdx.x;
    int t = threadIdx.x;

    if (bx >= 3456) {                        // weight prep
        int e = (bx - 3456) * 256 + t;
        if (e < 64 * 32 * 27) {
            int oc = e / 864;
            int r = e - oc * 864;
            int ci = r / 27;
            int tap = r - ci * 27;
            w1h[oc * 864 + tap * 32 + ci] = (_Float16)w1[e];
        }
        int e2 = e - 55296;
        if (e2 >= 0 && e2 < 224 * 64) {
            int oc = e2 >> 6, k = e2 & 63;
            w2h[e2] = (oc < 216) ? (_Float16)w2[oc * 64 + k] : (_Float16)0.f;
        }
        return;
    }

    int which = bx >= 1728;
    int v0 = (which ? bx - 1728 : bx) * 64;
    const float* s = which ? x : feat;
    _Float16* dt = which ? xT : featT;

    for (int i = t; i < 1024; i += 256) {
        int c2 = i >> 6, dv = i & 63;
        f16x2 v;
        v.x = (_Float16)s[(2 * c2) * NVOX + v0 + dv];
        v.y = (_Float16)s[(2 * c2 + 1) * NVOX + v0 + dv];
        *(f16x2*)(tile + dv * 36 + c2 * 2) = v;
    }
    __syncthreads();
    for (int i = t; i < 512; i += 256) {
        int dv = i >> 3, ch = i & 7;
        f16x4 v = *(const f16x4*)(tile + dv * 36 + ch * 4);
        *(f16x4*)(dt + (v0 + dv) * 32 + ch * 4) = v;
    }
}

// ---------------------------------------------------------------------------
// K1: fully fused per (d,h) row of 48 voxels, 512 threads (8 waves).
//  phase A: stage featT 3x3 halo -> X [450 col][40 f16]   (36 KB)
//  phase B: conv3x3x3 + SiLU via MFMA (12 16x16 tiles over 8 waves)
//  phase C: h -> hl [48 px][72 f16] in LDS (aliases X; no HBM round-trip)
//  phase D: conv1x1 (64->216) via MFMA -> mbuf [8 sub][48 vox][28 f32] (43 KB)
//  phase E: stage xT halo -> X (overwrites hl) ; softmax(27) in mbuf
//  phase F: 27-tap convex combination -> out (full 384B rows per block)
// LDS total 79,008 B -> 2 blocks/CU, 16 waves/CU.
// ---------------------------------------------------------------------------
__global__ __launch_bounds__(512, 4) void k_main(
    const _Float16* __restrict__ featT, const _Float16* __restrict__ xT,
    const _Float16* __restrict__ w1h, const float* __restrict__ b1,
    const _Float16* __restrict__ w2h, const float* __restrict__ b2,
    float* __restrict__ out)
{
    __shared__ float smem[19752];              // 79,008 B
    float* mbuf = smem;                         // [8][48][28] f32
    _Float16* X  = (_Float16*)(smem + 10752);   // [450][40] f16 staging
    _Float16* hl = (_Float16*)(smem + 10752);   // [48][72] f16 (aliases X)

    int bx = xcd_swizzle(blockIdx.x, gridDim.x);
    int d = bx / 48, hh = bx - d * 48;
    int t = threadIdx.x;

    // ---- phase A: stage featT neighborhood (replicate-clamped)
    for (int i = t; i < 1800; i += 512) {
        int col = i >> 2, chunk = i & 3;        // col = dzdy*50 + px
        int dzdy = col / 50;
        int px = col - dzdy * 50;
        int dz = dzdy / 3, dy = dzdy - dz * 3;
        int zz = min(max(d + dz - 1, 0), 47);
        int yy = min(max(hh + dy - 1, 0), 47);
        int xx = min(max(px - 1, 0), 47);
        int vox = (zz * 48 + yy) * 48 + xx;
        *(f16x8*)(X + col * 40 + chunk * 8) =
            *(const f16x8*)(featT + vox * 32 + chunk * 8);
    }
    __syncthreads();

    int wid = t >> 6;                           // 0..7
    int lane = t & 63;
    int mcol = lane & 15;
    int q = lane >> 4;
    int ocs = wid & 3;                          // oc strip for conv1

    // ---- phase B: conv1 MFMA. waves 0-3: px blocks {0,2}; waves 4-7: {1}
    f32x4 c1a = {0.f, 0.f, 0.f, 0.f};
    f32x4 c1b = {0.f, 0.f, 0.f, 0.f};
    {
        const _Float16* wbase = w1h + (ocs * 16 + mcol) * 864 + q * 8;
#pragma unroll 3
        for (int dzdy = 0; dzdy < 9; ++dzdy) {
            const _Float16* brow = X + (dzdy * 50 + mcol) * 40 + q * 8;
            const _Float16* wrow = wbase + dzdy * 96;
#pragma unroll
            for (int dx = 0; dx < 3; ++dx) {
                f16x8 av = *(const f16x8*)(wrow + dx * 32);
                const _Float16* bb = brow + dx * 40;
                if (wid < 4) {
                    f16x8 b0 = *(const f16x8*)(bb);
                    f16x8 b2v = *(const f16x8*)(bb + 32 * 40);
                    c1a = __builtin_amdgcn_mfma_f32_16x16x32_f16(av, b0, c1a, 0, 0, 0);
                    c1b = __builtin_amdgcn_mfma_f32_16x16x32_f16(av, b2v, c1b, 0, 0, 0);
                } else {
                    f16x8 b1v = *(const f16x8*)(bb + 16 * 40);
                    c1a = __builtin_amdgcn_mfma_f32_16x16x32_f16(av, b1v, c1a, 0, 0, 0);
                }
            }
        }
    }
    __syncthreads();                            // all X reads done

    // ---- phase C: bias + SiLU -> hl [px][72] f16 (aliases X head)
    {
        float4 bv = ((const float4*)b1)[ocs * 4 + q];
        int pxb0 = (wid < 4) ? 0 : 1;
        int px0 = pxb0 * 16 + mcol;
        f16x4 o; float s;
        s = c1a[0] + bv.x; o.x = (_Float16)(s / (1.f + __expf(-s)));
        s = c1a[1] + bv.y; o.y = (_Float16)(s / (1.f + __expf(-s)));
        s = c1a[2] + bv.z; o.z = (_Float16)(s / (1.f + __expf(-s)));
        s = c1a[3] + bv.w; o.w = (_Float16)(s / (1.f + __expf(-s)));
        *(f16x4*)(hl + px0 * 72 + ocs * 16 + q * 4) = o;
        if (wid < 4) {
            int px1 = 32 + mcol;
            s = c1b[0] + bv.x; o.x = (_Float16)(s / (1.f + __expf(-s)));
            s = c1b[1] + bv.y; o.y = (_Float16)(s / (1.f + __expf(-s)));
            s = c1b[2] + bv.z; o.z = (_Float16)(s / (1.f + __expf(-s)));
            s = c1b[3] + bv.w; o.w = (_Float16)(s / (1.f + __expf(-s)));
            *(f16x4*)(hl + px1 * 72 + ocs * 16 + q * 4) = o;
        }
    }
    __syncthreads();                            // hl complete

    // ---- phase D: conv2 MFMA, 42 tiles (14 mt x 3 nt) over 8 waves
    for (int tt = wid; tt < 42; tt += 8) {
        int mt = tt / 3, nt = tt - mt * 3;
        float bias[4];
#pragma unroll
        for (int rr = 0; rr < 4; ++rr) {
            int oc = mt * 16 + q * 4 + rr;
            bias[rr] = (oc < 216) ? b2[oc] : 0.f;
        }
        f32x4 acc = {bias[0], bias[1], bias[2], bias[3]};
#pragma unroll
        for (int ks = 0; ks < 2; ++ks) {
            f16x8 av = *(const f16x8*)(w2h + (mt * 16 + mcol) * 64 + ks * 32 + q * 8);
            f16x8 bv = *(const f16x8*)(hl + (nt * 16 + mcol) * 72 + ks * 32 + q * 8);
            acc = __builtin_amdgcn_mfma_f32_16x16x32_f16(av, bv, acc, 0, 0, 0);
        }
        int vox = nt * 16 + mcol;
#pragma unroll
        for (int rr = 0; rr < 4; ++rr) {
            int oc = mt * 16 + q * 4 + rr;
            if (oc < 216) {
                int sub = oc / 27;
                int n = oc - sub * 27;
                mbuf[(sub * 48 + vox) * 28 + n] = acc[rr];
            }
        }
    }
    __syncthreads();                            // mbuf complete, hl dead

    // ---- phase E: stage xT halo into X (overwrites hl) + softmax in mbuf
    for (int i = t; i < 1800; i += 512) {
        int col = i >> 2, chunk = i & 3;
        int dzdy = col / 50;
        int px = col - dzdy * 50;
        int dz = dzdy / 3, dy = dzdy - dz * 3;
        int zz = min(max(d + dz - 1, 0), 47);
        int yy = min(max(hh + dy - 1, 0), 47);
        int xx = min(max(px - 1, 0), 47);
        int vox = (zz * 48 + yy) * 48 + xx;
        *(f16x8*)(X + col * 40 + chunk * 8) =
            *(const f16x8*)(xT + vox * 32 + chunk * 8);
    }
    if (t < 384) {                              // 8 sub x 48 vox rows
        int sub = t / 48;
        int vox = t - sub * 48;
        float4* p4p = (float4*)(mbuf + (sub * 48 + vox) * 28);
        float4 v[7];
#pragma unroll
        for (int g = 0; g < 7; ++g) v[g] = p4p[g];
        float mx = fmaxf(fmaxf(v[6].x, v[6].y), v[6].z);
#pragma unroll
        for (int g = 0; g < 6; ++g)
            mx = fmaxf(mx, fmaxf(fmaxf(v[g].x, v[g].y), fmaxf(v[g].z, v[g].w)));
        float s = 0.f;
#pragma unroll
        for (int g = 0; g < 7; ++g) {
            v[g].x = __expf(v[g].x - mx);
            v[g].y = __expf(v[g].y - mx);
            v[g].z = __expf(v[g].z - mx);
            v[g].w = __expf(v[g].w - mx);
        }
        v[6].w = 0.f;                           // tap 27 pad
#pragma unroll
        for (int g = 0; g < 7; ++g) s += v[g].x + v[g].y + v[g].z + v[g].w;
        float inv = 1.f / s;
#pragma unroll
        for (int g = 0; g < 7; ++g) {
            v[g].x *= inv; v[g].y *= inv; v[g].z *= inv; v[g].w *= inv;
            p4p[g] = v[g];
        }
    }
    __syncthreads();

    // ---- phase F: out[c][2d+i][2h+j][2w+k] = sum_n p[sub][w][n]*x[c][nb(w,n)]
    float4* smem4 = (float4*)smem;
    int u = t & 255;
    int half = t >> 8;
    int w0 = half * 24;
    int tx = u & 7, ty = u >> 3;
    int cq = ty & 7, sp = ty >> 3;              // sp -> (i,j)
    float4 acc[2][3];
#pragma unroll
    for (int s = 0; s < 2; ++s)
#pragma unroll
        for (int wi = 0; wi < 3; ++wi)
            acc[s][wi] = make_float4(0.f, 0.f, 0.f, 0.f);

#pragma unroll
    for (int g = 0; g < 7; ++g) {
        float4 p4[2][3];
#pragma unroll
        for (int s = 0; s < 2; ++s)
#pragma unroll
            for (int wi = 0; wi < 3; ++wi)
                p4[s][wi] = smem4[((sp * 2 + s) * 48 + w0 + tx + wi * 8) * 7 + g];
#pragma unroll
        for (int j = 0; j < 4; ++j) {
            int n = g * 4 + j;
            if (n < 27) {
                int dz = n / 9;
                int rem = n - dz * 9;
                int dy = rem / 3, dx = rem - dy * 3;
#pragma unroll
                for (int wi = 0; wi < 3; ++wi) {
                    int col = (dz * 3 + dy) * 50 + w0 + tx + wi * 8 + dx;
                    f16x4 xr = *(const f16x4*)(X + col * 40 + cq * 4);
                    float4 xv = make_float4((float)xr.x, (float)xr.y,
                                            (float)xr.z, (float)xr.w);
                    fmas4(acc[0][wi], xv, comp4(p4[0][wi], j));
                    fmas4(acc[1][wi], xv, comp4(p4[1][wi], j));
                }
            }
        }
    }

    int i_ = sp >> 1, j_ = sp & 1;
    int rowz = 2 * d + i_;
    int rowy = 2 * hh + j_;
#pragma unroll
    for (int wi = 0; wi < 3; ++wi) {
        int wg = w0 + tx + wi * 8;
#pragma unroll
        for (int cc = 0; cc < 4; ++cc) {
            int c = cq * 4 + cc;
            float2 v;
            v.x = comp4(acc[0][wi], cc);        // k = 0
            v.y = comp4(acc[1][wi], cc);        // k = 1
            *(float2*)(out + (((size_t)c * 96 + rowz) * 96 + rowy) * 96 + 2 * wg) = v;
        }
    }
}

extern "C" void kernel_launch(void* const* d_in, const int* in_sizes, int n_in,
                              void* d_out, int out_size, void* d_ws, size_t ws_size,
                              hipStream_t stream) {
    const float* x    = (const float*)d_in[0];
    const float* feat = (const float*)d_in[1];
    const float* w1   = (const float*)d_in[2];
    const float* b1   = (const float*)d_in[3];
    const float* w2   = (const float*)d_in[4];
    const float* b2   = (const float*)d_in[5];
    float* out = (float*)d_out;

    _Float16* w1h   = (_Float16*)d_ws;                       // 110,592 B
    _Float16* w2h   = (_Float16*)((char*)d_ws + 110592);     //  28,672 B
    _Float16* featT = (_Float16*)((char*)d_ws + 139264);     // 7,077,888 B
    _Float16* xT    = (_Float16*)((char*)d_ws + 7217152);    // 7,077,888 B

    k_prep<<<3728, 256, 0, stream>>>(feat, x, w1, w2, featT, xT, w1h, w2h);
    k_main<<<2304, 512, 0, stream>>>(featT, xT, w1h, b1, w2h, b2, out);
}